// Round 2
// baseline (204.392 us; speedup 1.0000x reference)
//
#include <hip/hip_runtime.h>
#include <hip/hip_bf16.h>

// Dice metric. inputs (16,8,512,512) f32, targets (16,1,512,512) i32.
// dice[b,c] = 2*tps / (pred_count + tgt_count + eps); out[b] = mean_{c=1..7}.
// Memory-bound: 151 MB single-pass read -> ~24 us floor at 6.3 TB/s.
// R1: atomics+memset -> per-block private slots (no init, no atomics).
// R2: occupancy 16 -> 32 waves/CU. 512-thread blocks (8 waves/block,
//     4 blocks/CU) + incremental argmax (running m/am, ~30 live VGPRs) +
//     __launch_bounds__(512,8) to keep VGPR<=64. ws layout unchanged.
// R3: no measurement returned (GPU acquisition timeout 2x) — resubmitting
//     R2 unchanged for its first actual bench.

#define HW_PIX (512 * 512)
#define NCH 8
#define NB 16
#define EPS 1e-5f

constexpr int TPB = 512;            // threads per block (8 waves)
constexpr int BPB = 64;             // blocks per batch -> 1024 blocks total
constexpr int PIX_PER_BLOCK = HW_PIX / BPB;          // 4096
constexpr int ITERS = PIX_PER_BLOCK / (TPB * 4);     // 2 float4-iters/thread

// ws layout: uint partial[1024][8]; partial[(b*64+bx)][c] = (den<<16)|tps

__global__ __launch_bounds__(TPB, 8) void dice_count_kernel(
    const float* __restrict__ in, const int* __restrict__ tgt,
    unsigned int* __restrict__ ws) {
  const int b = blockIdx.y;
  const int t = threadIdx.x;
  const float* inb = in + (size_t)b * NCH * HW_PIX;
  const int* tb = tgt + (size_t)b * HW_PIX;
  const int base = blockIdx.x * PIX_PER_BLOCK;

  // packed 8x8-bit per-channel counters; max 8 per field (8 pixels/thread)
  unsigned long long pc = 0ull, tc = 0ull, tp = 0ull;

  for (int i = 0; i < ITERS; ++i) {
    const int pix = base + i * (TPB * 4) + t * 4;

    int4 tg4 = *reinterpret_cast<const int4*>(tb + pix);
    float4 m4 = *reinterpret_cast<const float4*>(inb + pix);   // c = 0
    float mv[4] = {m4.x, m4.y, m4.z, m4.w};
    int am[4] = {0, 0, 0, 0};

#pragma unroll
    for (int c = 1; c < NCH; ++c) {
      float4 f = *reinterpret_cast<const float4*>(inb + (size_t)c * HW_PIX + pix);
      float fv[4] = {f.x, f.y, f.z, f.w};
#pragma unroll
      for (int j = 0; j < 4; ++j) {
        // strict > keeps FIRST max (matches jnp.argmax tie-break)
        if (fv[j] > mv[j]) { mv[j] = fv[j]; am[j] = c; }
      }
    }

    const int tga[4] = {tg4.x, tg4.y, tg4.z, tg4.w};
#pragma unroll
    for (int j = 0; j < 4; ++j) {
      const unsigned long long s = 1ull << (am[j] * 8);
      pc += s;
      tc += 1ull << (tga[j] * 8);
      if (am[j] == tga[j]) tp += s;
    }
  }

  // per-channel packed (den<<16)|tps; per-lane den<=16 -> 64-lane sum <=1024,
  // block sum den<=8192, tps<=4096 -> no cross-field carry in 16-bit fields.
  unsigned int packed[NCH];
#pragma unroll
  for (int c = 0; c < NCH; ++c) {
    unsigned den = (unsigned)((pc >> (8 * c)) & 0xFF) +
                   (unsigned)((tc >> (8 * c)) & 0xFF);
    unsigned tps = (unsigned)((tp >> (8 * c)) & 0xFF);
    packed[c] = (den << 16) | tps;
  }

  // wave (64-lane) reduction
#pragma unroll
  for (int off = 32; off > 0; off >>= 1) {
#pragma unroll
    for (int c = 0; c < NCH; ++c)
      packed[c] += __shfl_down(packed[c], off);
  }

  __shared__ unsigned int s[TPB / 64][NCH];
  const int wave = t >> 6;
  const int lane = t & 63;
  if (lane == 0) {
#pragma unroll
    for (int c = 0; c < NCH; ++c) s[wave][c] = packed[c];
  }
  __syncthreads();

  if (t < NCH) {
    unsigned int sum = 0;
#pragma unroll
    for (int w = 0; w < TPB / 64; ++w) sum += s[w][t];
    ws[((size_t)b * BPB + blockIdx.x) * NCH + t] = sum;  // private slot, no atomics
  }
}

__global__ __launch_bounds__(128) void dice_finalize_kernel(
    const unsigned int* __restrict__ ws, float* __restrict__ out) {
  const int t = threadIdx.x;     // 128 threads: t = b*8 + c
  const int b = t >> 3;
  const int c = t & 7;

  unsigned int tps = 0, den = 0;
#pragma unroll
  for (int i = 0; i < BPB; ++i) {
    const unsigned int p = ws[((size_t)b * BPB + i) * NCH + c];
    tps += p & 0xFFFFu;
    den += p >> 16;
  }
  float dice = (c >= 1) ? (2.0f * (float)tps / ((float)den + EPS)) : 0.0f;

  // sum across the 8 channels of each batch (lanes b*8..b*8+7 within a wave)
  dice += __shfl_down(dice, 4, 8);
  dice += __shfl_down(dice, 2, 8);
  dice += __shfl_down(dice, 1, 8);
  if (c == 0) out[b] = dice * (1.0f / 7.0f);
}

extern "C" void kernel_launch(void* const* d_in, const int* in_sizes, int n_in,
                              void* d_out, int out_size, void* d_ws, size_t ws_size,
                              hipStream_t stream) {
  const float* in = (const float*)d_in[0];
  const int* tgt = (const int*)d_in[1];
  float* out = (float*)d_out;
  unsigned int* ws = (unsigned int*)d_ws;

  dim3 grid(BPB, NB);
  dice_count_kernel<<<grid, TPB, 0, stream>>>(in, tgt, ws);
  dice_finalize_kernel<<<1, 128, 0, stream>>>(ws, out);
}

// Round 4
// 188.015 us; speedup vs baseline: 1.0871x; 1.0871x over previous
//
#include <hip/hip_runtime.h>
#include <hip/hip_bf16.h>

// Dice metric. inputs (16,8,512,512) f32, targets (16,1,512,512) i32.
// dice[b,c] = 2*tps / (pred_count + tgt_count + eps); out[b] = mean_{c=1..7}.
// Memory-bound: 151 MB single-pass read -> ~24 us floor at 6.3 TB/s.
// R1: atomics+memset -> per-block private slots (no init, no atomics).
// R2: 512-thr blocks, 32 waves/CU: NULL vs 16 waves (204.4 us).
//     rocprof: timed region contains two 512 MiB harness ws-poison fills
//     (~78 us each @ 6.9 TB/s); our kernels <78 us (absent from top-5).
//     Controllable part ~47 us vs 24 us floor.
// R4: nontemporal dwordx4 loads (L3 wiped by fills each iter anyway),
//     16 px/thread fully unrolled (ITERS=4) incremental argmax,
//     __launch_bounds__(256,4): <=128 VGPR, 1024 blocks = whole grid
//     resident, compiler free to pipeline ~2 iterations of loads ahead.
// R5: acquisition timeout — resubmitting R4 unchanged for its first bench.

#define HW_PIX (512 * 512)
#define NCH 8
#define NB 16
#define EPS 1e-5f

constexpr int TPB = 256;            // threads per block (4 waves)
constexpr int BPB = 64;             // blocks per batch -> 1024 blocks total
constexpr int PIX_PER_BLOCK = HW_PIX / BPB;          // 4096
constexpr int ITERS = PIX_PER_BLOCK / (TPB * 4);     // 4 float4-iters/thread

typedef float f32x4 __attribute__((ext_vector_type(4)));
typedef int i32x4 __attribute__((ext_vector_type(4)));

__device__ __forceinline__ f32x4 ntload_f4(const float* p) {
  return __builtin_nontemporal_load(reinterpret_cast<const f32x4*>(p));
}
__device__ __forceinline__ i32x4 ntload_i4(const int* p) {
  return __builtin_nontemporal_load(reinterpret_cast<const i32x4*>(p));
}

// ws layout: uint partial[1024][8]; partial[(b*64+bx)][c] = (den<<16)|tps

__global__ __launch_bounds__(TPB, 4) void dice_count_kernel(
    const float* __restrict__ in, const int* __restrict__ tgt,
    unsigned int* __restrict__ ws) {
  const int b = blockIdx.y;
  const int t = threadIdx.x;
  const float* inb = in + (size_t)b * NCH * HW_PIX;
  const int* tb = tgt + (size_t)b * HW_PIX;
  const int base = blockIdx.x * PIX_PER_BLOCK;

  // packed 8x8-bit per-channel counters; max 16 per field (16 pixels/thread)
  unsigned long long pc = 0ull, tc = 0ull, tp = 0ull;

#pragma unroll
  for (int i = 0; i < ITERS; ++i) {
    const int pix = base + i * (TPB * 4) + t * 4;

    i32x4 tg4 = ntload_i4(tb + pix);
    f32x4 m4 = ntload_f4(inb + pix);                 // c = 0
    float mv[4] = {m4[0], m4[1], m4[2], m4[3]};
    int am[4] = {0, 0, 0, 0};

#pragma unroll
    for (int c = 1; c < NCH; ++c) {
      f32x4 f = ntload_f4(inb + (size_t)c * HW_PIX + pix);
#pragma unroll
      for (int j = 0; j < 4; ++j) {
        // strict > keeps FIRST max (matches jnp.argmax tie-break)
        if (f[j] > mv[j]) { mv[j] = f[j]; am[j] = c; }
      }
    }

#pragma unroll
    for (int j = 0; j < 4; ++j) {
      const int tg = tg4[j];
      const unsigned long long s = 1ull << (am[j] * 8);
      pc += s;
      tc += 1ull << (tg * 8);
      if (am[j] == tg) tp += s;
    }
  }

  // per-channel packed (den<<16)|tps; per-lane den<=32 -> 64-lane sum <=2048,
  // block sum den<=8192, tps<=4096 -> no cross-field carry in 16-bit fields.
  unsigned int packed[NCH];
#pragma unroll
  for (int c = 0; c < NCH; ++c) {
    unsigned den = (unsigned)((pc >> (8 * c)) & 0xFF) +
                   (unsigned)((tc >> (8 * c)) & 0xFF);
    unsigned tps = (unsigned)((tp >> (8 * c)) & 0xFF);
    packed[c] = (den << 16) | tps;
  }

  // wave (64-lane) reduction
#pragma unroll
  for (int off = 32; off > 0; off >>= 1) {
#pragma unroll
    for (int c = 0; c < NCH; ++c)
      packed[c] += __shfl_down(packed[c], off);
  }

  __shared__ unsigned int s[TPB / 64][NCH];
  const int wave = t >> 6;
  const int lane = t & 63;
  if (lane == 0) {
#pragma unroll
    for (int c = 0; c < NCH; ++c) s[wave][c] = packed[c];
  }
  __syncthreads();

  if (t < NCH) {
    unsigned int sum = 0;
#pragma unroll
    for (int w = 0; w < TPB / 64; ++w) sum += s[w][t];
    ws[((size_t)b * BPB + blockIdx.x) * NCH + t] = sum;  // private slot, no atomics
  }
}

__global__ __launch_bounds__(128) void dice_finalize_kernel(
    const unsigned int* __restrict__ ws, float* __restrict__ out) {
  const int t = threadIdx.x;     // 128 threads: t = b*8 + c
  const int b = t >> 3;
  const int c = t & 7;

  unsigned int tps = 0, den = 0;
#pragma unroll
  for (int i = 0; i < BPB; ++i) {
    const unsigned int p = ws[((size_t)b * BPB + i) * NCH + c];
    tps += p & 0xFFFFu;
    den += p >> 16;
  }
  float dice = (c >= 1) ? (2.0f * (float)tps / ((float)den + EPS)) : 0.0f;

  // sum across the 8 channels of each batch (lanes b*8..b*8+7 within a wave)
  dice += __shfl_down(dice, 4, 8);
  dice += __shfl_down(dice, 2, 8);
  dice += __shfl_down(dice, 1, 8);
  if (c == 0) out[b] = dice * (1.0f / 7.0f);
}

extern "C" void kernel_launch(void* const* d_in, const int* in_sizes, int n_in,
                              void* d_out, int out_size, void* d_ws, size_t ws_size,
                              hipStream_t stream) {
  const float* in = (const float*)d_in[0];
  const int* tgt = (const int*)d_in[1];
  float* out = (float*)d_out;
  unsigned int* ws = (unsigned int*)d_ws;

  dim3 grid(BPB, NB);
  dice_count_kernel<<<grid, TPB, 0, stream>>>(in, tgt, ws);
  dice_finalize_kernel<<<1, 128, 0, stream>>>(ws, out);
}